// Round 5
// baseline (357.171 us; speedup 1.0000x reference)
//
#include <hip/hip_runtime.h>

// DownSample fused: gather(knn) -> LayerNorm(C=128) -> Linear(128->256, bf16 MFMA) -> maxpool(k=16)
// Outputs concatenated: out[m,256] f32 | n_p[m,3] f32 | n_o[4] as f32
//
// R5: async-DMA staging. global_load_lds (16B) pulls raw f32 neighbor rows into
// a double-buffered LDS tile (2 x 32 rows x 512B = 32 KB). Per iteration:
//   __syncthreads (drains DMA issued a FULL iteration ago -> ~0 stall)
//   -> issue next buffer's DMA -> consume current (ds_read f32 in A-frag order,
//   LN via qd-shuffles, f2bf, MFMA, maxpool, store).
// Hiding window = whole iteration (~1000 cyc) vs R4's MFMA-section (~350 cyc).
// No pf registers, no producer ds_writes, perfectly coalesced 512B-row DMA.
// W' = W*nw bf16 register-resident; bias c = nb.W added after maxpool.

#define C_IN   128
#define C_OUT  256
#define KNN    16
#define LN_EPS 1e-5f
#define BQ     2
#define ROWS   (BQ * KNN)        // 32 rows per batch
#define TILE_F (ROWS * C_IN)     // floats per buffer (4096)
#define NBLK   1024

typedef __attribute__((ext_vector_type(8))) short  short8;
typedef __attribute__((ext_vector_type(8))) __bf16 bf16x8;
typedef __attribute__((ext_vector_type(4))) float  f32x4;

__device__ __forceinline__ short f2bf_bits(float f) {
    unsigned u = __float_as_uint(f);
    u += 0x7fffu + ((u >> 16) & 1u);   // round-to-nearest-even
    return (short)(u >> 16);
}

__device__ __forceinline__ void dma16(const void* g, void* l) {
    __builtin_amdgcn_global_load_lds(
        (const __attribute__((address_space(1))) void*)g,
        (__attribute__((address_space(3))) void*)l, 16, 0, 0);
}

__global__ __launch_bounds__(256) void fused_kernel(
    const float* __restrict__ x, const int* __restrict__ knn,
    const float* __restrict__ nw, const float* __restrict__ nb,
    const float* __restrict__ W,
    const float* __restrict__ n_p, const int* __restrict__ n_o,
    float* __restrict__ out, float* __restrict__ out_np, float* __restrict__ out_no,
    int mq, int npcnt)
{
    __shared__ __align__(16) float Ash[2 * TILE_F];   // 32 KB double buffer

    const int tid  = threadIdx.x;
    const int lane = tid & 63;
    const int wave = tid >> 6;          // wave w owns out cols [w*64, w*64+64)
    const int m16  = lane & 15;
    const int qd   = lane >> 4;
    const int half = lane >> 5;         // row within the 2-row DMA pair
    const int col  = lane & 31;         // 16B chunk within a 512B row

    const int b0 = blockIdx.x;
    const int g  = gridDim.x;
    const int nbat = (mq + BQ - 1) / BQ;
    const int maxflat = mq * KNN - 1;

    // ---- prime: issue DMA for batch b0 into buffer 0 (before the long preamble) ----
    int idxv[4];
    if (b0 < nbat) {
        #pragma unroll
        for (int c = 0; c < 4; ++c) {
            int flat = b0 * ROWS + wave * 8 + c * 2 + half;
            flat = flat > maxflat ? maxflat : flat;
            idxv[c] = knn[flat];
        }
        #pragma unroll
        for (int c = 0; c < 4; ++c) {
            const float* gp = x + (long long)idxv[c] * C_IN + col * 4;
            dma16(gp, &Ash[(wave * 8 + c * 2) * C_IN]);
        }
    }

    // ---- preamble: B fragments W'[n][k] = W[n][k]*nw[k] (bf16); c[n] = sum_k nb[k]W[n][k]
    short8 bfrag[4][4];                 // [n-tile][k-step]
    float  cpart[4] = {0.f, 0.f, 0.f, 0.f};
    #pragma unroll
    for (int s = 0; s < 4; ++s) {
        const int k0 = s * 32 + qd * 8;
        const float4 a0 = *(const float4*)(nw + k0);
        const float4 a1 = *(const float4*)(nw + k0 + 4);
        const float4 c0 = *(const float4*)(nb + k0);
        const float4 c1 = *(const float4*)(nb + k0 + 4);
        const float nwv[8] = {a0.x,a0.y,a0.z,a0.w,a1.x,a1.y,a1.z,a1.w};
        const float nbv[8] = {c0.x,c0.y,c0.z,c0.w,c1.x,c1.y,c1.z,c1.w};
        #pragma unroll
        for (int t = 0; t < 4; ++t) {
            const int n = wave * 64 + t * 16 + m16;
            const float4* wp = (const float4*)(W + n * C_IN + k0);
            const float4 w0 = wp[0], w1 = wp[1];
            const float wvv[8] = {w0.x,w0.y,w0.z,w0.w,w1.x,w1.y,w1.z,w1.w};
            short8 b;
            #pragma unroll
            for (int j = 0; j < 8; ++j) {
                b[j] = f2bf_bits(wvv[j] * nwv[j]);
                cpart[t] += nbv[j] * wvv[j];
            }
            bfrag[t][s] = b;
        }
    }
    #pragma unroll
    for (int t = 0; t < 4; ++t) {
        cpart[t] += __shfl_xor(cpart[t], 16);
        cpart[t] += __shfl_xor(cpart[t], 32);
    }
    const float cbias = (qd == 0) ? cpart[0] : (qd == 1) ? cpart[1]
                      : (qd == 2) ? cpart[2] : cpart[3];

    // ---- prefetch knn indices for batch b0+g ----
    {
        int bn = b0 + g; if (bn >= nbat) bn = (nbat > 0) ? (nbat - 1) : 0;
        #pragma unroll
        for (int c = 0; c < 4; ++c) {
            int flat = bn * ROWS + wave * 8 + c * 2 + half;
            flat = flat > maxflat ? maxflat : flat;
            idxv[c] = knn[flat];
        }
    }

    int buf = 0;
    for (int bat = b0; bat < nbat; bat += g) {
        // drains DMA issued one full iteration ago for buf -> near-zero stall
        __syncthreads();

        // ---- issue next batch's DMA into the other buffer ----
        if (bat + g < nbat) {
            #pragma unroll
            for (int c = 0; c < 4; ++c) {
                const float* gp = x + (long long)idxv[c] * C_IN + col * 4;
                dma16(gp, &Ash[(buf ^ 1) * TILE_F + (wave * 8 + c * 2) * C_IN]);
            }
        }
        // ---- prefetch indices for bat+2g ----
        {
            int bn = bat + 2 * g; if (bn >= nbat) bn = nbat - 1;
            #pragma unroll
            for (int c = 0; c < 4; ++c) {
                int flat = bn * ROWS + wave * 8 + c * 2 + half;
                flat = flat > maxflat ? maxflat : flat;
                idxv[c] = knn[flat];
            }
        }

        // ---- consume current buffer: 2 queries ----
        #pragma unroll
        for (int ql = 0; ql < BQ; ++ql) {
            const float* tb = &Ash[buf * TILE_F + (ql * 16 + m16) * C_IN];
            float v[32];
            #pragma unroll
            for (int s = 0; s < 4; ++s) {
                const f32x4 a = *(const f32x4*)(tb + s * 32 + qd * 8);
                const f32x4 b = *(const f32x4*)(tb + s * 32 + qd * 8 + 4);
                v[s*8+0]=a[0]; v[s*8+1]=a[1]; v[s*8+2]=a[2]; v[s*8+3]=a[3];
                v[s*8+4]=b[0]; v[s*8+5]=b[1]; v[s*8+6]=b[2]; v[s*8+7]=b[3];
            }
            float s1 = 0.f, s2 = 0.f;
            #pragma unroll
            for (int j = 0; j < 32; ++j) { s1 += v[j]; s2 += v[j] * v[j]; }
            s1 += __shfl_xor(s1, 16); s1 += __shfl_xor(s1, 32);
            s2 += __shfl_xor(s2, 16); s2 += __shfl_xor(s2, 32);
            const float mu   = s1 * (1.f / 128.f);
            const float rstd = rsqrtf(s2 * (1.f / 128.f) - mu * mu + LN_EPS);

            f32x4 acc[4] = {{0,0,0,0},{0,0,0,0},{0,0,0,0},{0,0,0,0}};
            #pragma unroll
            for (int s = 0; s < 4; ++s) {
                short8 a;
                #pragma unroll
                for (int j = 0; j < 8; ++j)
                    a[j] = f2bf_bits((v[s*8+j] - mu) * rstd);
                const bf16x8 av = __builtin_bit_cast(bf16x8, a);
                #pragma unroll
                for (int t = 0; t < 4; ++t)
                    acc[t] = __builtin_amdgcn_mfma_f32_16x16x32_bf16(
                        av, __builtin_bit_cast(bf16x8, bfrag[t][s]), acc[t], 0, 0, 0);
            }

            float r[4];
            #pragma unroll
            for (int t = 0; t < 4; ++t) {
                float vv = fmaxf(fmaxf(acc[t][0], acc[t][1]), fmaxf(acc[t][2], acc[t][3]));
                vv = fmaxf(vv, __shfl_xor(vv, 16));
                vv = fmaxf(vv, __shfl_xor(vv, 32));
                r[t] = vv;
            }
            const float vout = ((qd == 0) ? r[0] : (qd == 1) ? r[1]
                              : (qd == 2) ? r[2] : r[3]) + cbias;
            const int q = bat * BQ + ql;
            if (q < mq) out[q * C_OUT + wave * 64 + lane] = vout;
        }
        buf ^= 1;
    }

    // ---- passthrough outputs ----
    const int gtid = blockIdx.x * 256 + tid;
    const int gstr = g * 256;
    const int np4 = npcnt >> 2;
    for (int i = gtid; i < np4; i += gstr)
        ((float4*)out_np)[i] = ((const float4*)n_p)[i];
    for (int i = (np4 << 2) + gtid; i < npcnt; i += gstr) out_np[i] = n_p[i];
    if (gtid < 4) out_no[gtid] = (float)n_o[gtid];
}

extern "C" void kernel_launch(void* const* d_in, const int* in_sizes, int n_in,
                              void* d_out, int out_size, void* d_ws, size_t ws_size,
                              hipStream_t stream)
{
    const float* x   = (const float*)d_in[1];
    const float* n_p = (const float*)d_in[3];
    const int*   knn = (const int*)  d_in[4];
    const int*   n_o = (const int*)  d_in[5];
    const float* nw  = (const float*)d_in[6];
    const float* nb  = (const float*)d_in[7];
    const float* W   = (const float*)d_in[8];
    float* out = (float*)d_out;

    const int mq    = in_sizes[4] / KNN;   // 50000
    const int npcnt = in_sizes[3];         // 150000
    float* out_np = out + (size_t)mq * C_OUT;
    float* out_no = out_np + npcnt;

    hipLaunchKernelGGL(fused_kernel, dim3(NBLK), dim3(256), 0, stream,
                       x, knn, nw, nb, W, n_p, n_o, out, out_np, out_no, mq, npcnt);
}